// Round 8
// baseline (215.384 us; speedup 1.0000x reference)
//
#include <hip/hip_runtime.h>
#include <hip/hip_bf16.h>

typedef unsigned short ushort_t;
typedef _Float16 half_t;
typedef __attribute__((ext_vector_type(8))) _Float16 h8;     // 8 fp16 (K=32 MFMA A/B frag)
typedef __attribute__((ext_vector_type(8))) short short8;
typedef __attribute__((ext_vector_type(4))) float f32x4;
typedef __attribute__((ext_vector_type(4))) float f4;

#define NB 4
#define SS 1024
#define HH 2048
#define NH 16
#define DD 128
#define MM (NB*SS)          // 4096 rows
#define NTOT 2304           // 2048 Q cols | 128 K | 128 V
#define COL_K 2048
#define COL_V 2176
#define KVB 64
#define L2E 1.44269504089f

__device__ __forceinline__ ushort_t f2h(float x) {
    half_t h = (half_t)x;
    return *(ushort_t*)&h;
}
__device__ __forceinline__ f32x4 mfma16h(h8 a, h8 b, f32x4 c) {
    return __builtin_amdgcn_mfma_f32_16x16x32_f16(a, b, c, 0, 0, 0);
}
__device__ __forceinline__ void load_lds16(const ushort_t* g, ushort_t* l) {
    __builtin_amdgcn_global_load_lds(
        (const __attribute__((address_space(1))) unsigned int*)g,
        (__attribute__((address_space(3))) unsigned int*)l,
        16, 0, 0);
}

// ---------------- f32 -> fp16 convert (hidden states) ----------------
__global__ void k_cvt(const float* __restrict__ src, ushort_t* __restrict__ dst, int n) {
    int i = (blockIdx.x * blockDim.x + threadIdx.x) * 8;
    if (i + 7 < n) {
        f4 a = *(const f4*)(src + i);
        f4 b = *(const f4*)(src + i + 4);
        short8 o;
        #pragma unroll
        for (int j = 0; j < 4; ++j) { o[j] = (short)f2h(a[j]); o[4 + j] = (short)f2h(b[j]); }
        *(short8*)(dst + i) = o;
    }
}

// ---------------- tiled weight transpose+convert: W[n][H][Dd] -> T[n*Dd+d][HH] ----------------
__global__ __launch_bounds__(256) void k_tw(const float* __restrict__ W,
                                            ushort_t* __restrict__ T, int Dd) {
    __shared__ ushort_t t[64][74];
    const int n = blockIdx.z;
    const int h0 = blockIdx.x * 64, d0 = blockIdx.y * 64;
    const int r = threadIdx.x >> 2, cg = (threadIdx.x & 3) * 16;
    const float* src = W + ((size_t)n * HH + h0 + r) * Dd + d0 + cg;
    #pragma unroll
    for (int v = 0; v < 4; ++v) {
        f4 a = *(const f4*)(src + v * 4);
        #pragma unroll
        for (int j = 0; j < 4; ++j) t[r][cg + v * 4 + j] = f2h(a[j]);
    }
    __syncthreads();
    short8 o0, o1;
    #pragma unroll
    for (int j = 0; j < 8; ++j) { o0[j] = (short)t[cg + j][r]; o1[j] = (short)t[cg + 8 + j][r]; }
    ushort_t* dst = T + ((size_t)(n * Dd + d0 + r)) * HH + h0 + cg;
    *(short8*)dst = o0;
    *(short8*)(dst + 8) = o1;
}

// ---------------- fp16 GEMM: O[M][NTOT] = A[M][HH] * B[NTOT][HH]^T + bias(fused) --------
__global__ __launch_bounds__(256) void k_gemm(
    const ushort_t* __restrict__ A, const ushort_t* __restrict__ B,
    const float* __restrict__ bq, const float* __restrict__ bk,
    const float* __restrict__ bvv, ushort_t* __restrict__ O) {

    constexpr int BK = 32;
    __shared__ ushort_t sA[128 * BK], sB[128 * BK];

    const int bid = blockIdx.x;
    const int swz = (bid & 7) * 72 + (bid >> 3);     // 576/8 = 72 per XCD, bijective
    const int m0 = (swz & 31) * 128;
    const int n0 = (swz >> 5) * 128;

    const int tid = threadIdx.x;
    const int w = tid >> 6, l = tid & 63;
    const int wr = w >> 1, wc = w & 1;
    f32x4 acc[4][4] = {};

    for (int kt = 0; kt < HH / BK; ++kt) {
        const int k0 = kt * BK;
        #pragma unroll
        for (int c = 0; c < 2; ++c) {
            int chunk = c * 4 + w;
            int idx = chunk * 512 + l * 8;
            int row = idx >> 5, kc = idx & 31;
            load_lds16(A + (size_t)(m0 + row) * HH + k0 + kc, &sA[chunk * 512]);
            load_lds16(B + (size_t)(n0 + row) * HH + k0 + kc, &sB[chunk * 512]);
        }
        __syncthreads();

        h8 a[4], b[4];
        #pragma unroll
        for (int i = 0; i < 4; ++i) {
            int ra = wr * 64 + i * 16 + (l & 15);
            int rb = wc * 64 + i * 16 + (l & 15);
            a[i] = *(const h8*)&sA[ra * 32 + (l >> 4) * 8];
            b[i] = *(const h8*)&sB[rb * 32 + (l >> 4) * 8];
        }
        #pragma unroll
        for (int i = 0; i < 4; ++i)
            #pragma unroll
            for (int j = 0; j < 4; ++j)
                acc[i][j] = mfma16h(a[i], b[j], acc[i][j]);
        __syncthreads();
    }

    #pragma unroll
    for (int i = 0; i < 4; ++i) {
        int row = m0 + wr * 64 + i * 16 + ((l >> 4) << 2);
        #pragma unroll
        for (int j = 0; j < 4; ++j) {
            int col = n0 + wc * 64 + j * 16 + (l & 15);
            float bv = (col < COL_K) ? bq[col]
                     : (col < COL_V) ? bk[col - COL_K]
                                     : bvv[col - COL_V];
            #pragma unroll
            for (int r = 0; r < 4; ++r) {
                float cv = acc[i][j][r] + bv;
                O[(size_t)(row + r) * NTOT + col] = f2h(cv);
            }
        }
    }
}

// ---------------- V transpose: O cols [COL_V..COL_V+128) -> Vt[128][MM] ----------------
__global__ __launch_bounds__(256) void k_transpose_v(const ushort_t* __restrict__ O,
                                                     ushort_t* __restrict__ Vt) {
    __shared__ ushort_t t[64][74];
    const int tid = threadIdx.x;
    const int bx = blockIdx.x;       // MM/64
    const int by = blockIdx.y;       // 128/64
    int r = tid >> 2, cg = (tid & 3) * 16;
    const ushort_t* src = &O[(size_t)(bx * 64 + r) * NTOT + COL_V + by * 64 + cg];
    short8 v0 = *(const short8*)src;
    short8 v1 = *(const short8*)(src + 8);
    #pragma unroll
    for (int j = 0; j < 8; ++j) { t[r][cg + j] = (ushort_t)v0[j]; t[r][cg + 8 + j] = (ushort_t)v1[j]; }
    __syncthreads();
    short8 o0, o1;
    #pragma unroll
    for (int j = 0; j < 8; ++j) { o0[j] = (short)t[cg + j][r]; o1[j] = (short)t[cg + 8 + j][r]; }
    ushort_t* dst = &Vt[(size_t)(by * 64 + r) * MM + bx * 64 + cg];
    *(short8*)dst = o0;
    *(short8*)(dst + 8) = o1;
}

// ---------------- flash attention: K via LDS, V via L2 (m169 pattern) ----------------
// grid (S/128, N, B), 512 thr = 8 waves x 16 q-rows. Permuted swapped QK^T (zero-shuffle
// K=32 PV fragments); V^T read directly from global (L2-resident, frees LDS port).
__global__ __launch_bounds__(512, 4) void k_attn(
    const ushort_t* __restrict__ O, const ushort_t* __restrict__ Vt,
    float* __restrict__ Out) {

    __shared__ ushort_t sK[2][KVB * 128];     // [t][128], mask (t&3)|((t>>3)&1)<<2, dbuf

    const int tid = threadIdx.x;
    const int w = tid >> 6, l = tid & 63;     // w in [0,8)
    const int lg = l >> 4, li = l & 15;
    const int q0 = blockIdx.x * 128;
    const int n = blockIdx.y, b = blockIdx.z;

    // Q fragments: rows q0 + w*16 + li
    h8 qv[4];
    {
        size_t base = ((size_t)(b * SS + q0 + w * 16 + li)) * NTOT + n * 128 + lg * 8;
        #pragma unroll
        for (int kk = 0; kk < 4; ++kk)
            qv[kk] = *(const h8*)&O[base + kk * 32];
    }

    f32x4 accO[8] = {};
    float m2 = -3.0e38f;
    float lsum = 0.f;

    auto stage = [&](int bi, int t0) {
        #pragma unroll
        for (int c = 0; c < 2; ++c) {
            int seg = c * 8 + w;                         // 16 segs over 8 waves
            int oe = seg * 512 + l * 8;
            int row = oe >> 7;
            int mk = (row & 3) | (((row >> 3) & 1) << 2);
            int ce = (oe & 127) ^ (mk << 3);
            size_t g = (size_t)(b * SS + t0 + row) * NTOT + COL_K + ce;
            load_lds16(O + g, &sK[bi][seg * 512]);
        }
    };

    stage(0, 0);
    constexpr int NT = SS / KVB;   // 16
    const ushort_t* vtb = Vt + (size_t)b * SS;   // Vt[d][MM]: row d, col b*SS + t

    for (int it = 0; it < NT; ++it) {
        const int cur = it & 1;
        const int t0 = it * KVB;
        __syncthreads();                       // drains stage(cur)
        if (it + 1 < NT) stage(cur ^ 1, t0 + KVB);
        const ushort_t* sKc = sK[cur];

        // ---- QK^T, permuted A-rows: reg r of s[ts] = S[t=(ts&1)*32+lg*8+(ts>>1)*4+r][q=li]
        f32x4 s[4] = {};
        __builtin_amdgcn_s_setprio(1);
        #pragma unroll
        for (int ts = 0; ts < 4; ++ts) {
            int trow = (ts & 1) * 32 + ((li >> 2) << 3) + ((ts >> 1) << 2) + (li & 3);
            int mk = (trow & 3) | (((trow >> 3) & 1) << 2);
            #pragma unroll
            for (int kk = 0; kk < 4; ++kk) {
                h8 kv = *(const h8*)&sKc[trow * 128 + ((kk * 32 + lg * 8) ^ (mk << 3))];
                s[ts] = mfma16h(kv, qv[kk], s[ts]);     // A=K, B=Q -> S^T
            }
        }
        __builtin_amdgcn_s_setprio(0);

        // ---- in-register online softmax (row q = li; 16 t-values per lane)
        float v = fmaxf(fmaxf(s[0][0], s[0][1]), fmaxf(s[0][2], s[0][3]));
        #pragma unroll
        for (int ts = 1; ts < 4; ++ts)
            v = fmaxf(v, fmaxf(fmaxf(s[ts][0], s[ts][1]), fmaxf(s[ts][2], s[ts][3])));
        v = fmaxf(v, __shfl_xor(v, 16));
        v = fmaxf(v, __shfl_xor(v, 32));
        float pm2 = v * L2E;

        if (!__all(pm2 <= m2 + 11.54f)) {   // defer-max, THR = 8 nats
            float mn = fmaxf(m2, pm2);
            float scl = exp2f(m2 - mn);
            lsum *= scl;
            #pragma unroll
            for (int db = 0; db < 8; ++db)
                #pragma unroll
                for (int r = 0; r < 4; ++r) accO[db][r] *= scl;
            m2 = mn;
        }

        h8 pb[2];
        #pragma unroll
        for (int ts = 0; ts < 4; ++ts)
            #pragma unroll
            for (int r = 0; r < 4; ++r) {
                float p = exp2f(fmaf(s[ts][r], L2E, -m2));
                lsum += p;
                pb[ts & 1][((ts >> 1) << 2) + r] = (half_t)p;
            }

        // ---- PV: K=32; V^T straight from global (L2-hot), shared-port relief
        __builtin_amdgcn_s_setprio(1);
        #pragma unroll
        for (int db = 0; db < 8; ++db) {
            int d = db * 16 + li;
            const ushort_t* vrow = vtb + (size_t)d * MM + t0;
            #pragma unroll
            for (int ks = 0; ks < 2; ++ks) {
                h8 va = *(const h8*)&vrow[ks * 32 + lg * 8];
                accO[db] = mfma16h(va, pb[ks], accO[db]);
            }
        }
        __builtin_amdgcn_s_setprio(0);
    }

    // ---- epilogue: finish denominator, normalize, write f32 [B][N][S][D]
    lsum += __shfl_xor(lsum, 16);
    lsum += __shfl_xor(lsum, 32);
    float inv = 1.0f / lsum;
    int q = q0 + w * 16 + li;
    size_t base = (((size_t)b * NH + n) * SS + q) * DD;
    #pragma unroll
    for (int db = 0; db < 8; ++db) {
        f4 o;
        #pragma unroll
        for (int r = 0; r < 4; ++r) o[r] = accO[db][r] * inv;
        *(f4*)&Out[base + db * 16 + lg * 4] = o;
    }
}

// ---------------- workspace layout (bytes) ----------------
#define OFF_HC    ((size_t)0)                          // hidden fp16 [MM][HH]
#define OFF_BC    (OFF_HC + (size_t)MM*HH*2)           // Bcat fp16 [NTOT][HH]
#define OFF_O     (OFF_BC + (size_t)NTOT*HH*2)         // O fp16 [MM][NTOT]
#define OFF_VT    (OFF_O + (size_t)MM*NTOT*2)          // Vt fp16 [128][MM]

extern "C" void kernel_launch(void* const* d_in, const int* in_sizes, int n_in,
                              void* d_out, int out_size, void* d_ws, size_t ws_size,
                              hipStream_t stream) {
    const float* hs = (const float*)d_in[0];
    const float* Wq = (const float*)d_in[1];
    const float* bq = (const float*)d_in[2];
    const float* Wk = (const float*)d_in[3];
    const float* bk = (const float*)d_in[4];
    const float* Wv = (const float*)d_in[5];
    const float* bv = (const float*)d_in[6];
    float* out = (float*)d_out;
    char* ws = (char*)d_ws;

    ushort_t* hc   = (ushort_t*)(ws + OFF_HC);
    ushort_t* bcat = (ushort_t*)(ws + OFF_BC);
    ushort_t* Obuf = (ushort_t*)(ws + OFF_O);
    ushort_t* vt   = (ushort_t*)(ws + OFF_VT);

    // prep
    k_cvt<<<(MM*HH)/(256*8), 256, 0, stream>>>(hs, hc, MM*HH);
    dim3 gwq(HH/64, DD/64, NH);
    k_tw<<<gwq, 256, 0, stream>>>(Wq, bcat, DD);
    dim3 gwk(HH/64, DD/64, 1);
    k_tw<<<gwk, 256, 0, stream>>>(Wk, bcat + (size_t)COL_K*HH, DD);
    k_tw<<<gwk, 256, 0, stream>>>(Wv, bcat + (size_t)COL_V*HH, DD);

    // merged projection GEMM: 4096 x 2304 x 2048, bias fused
    k_gemm<<<(MM/128)*(NTOT/128), 256, 0, stream>>>(hc, bcat, bq, bk, bv, Obuf);

    // V transpose
    dim3 gt(MM/64, DD/64);
    k_transpose_v<<<gt, 256, 0, stream>>>(Obuf, vt);

    // attention
    dim3 ga(SS/128, NH, NB);
    k_attn<<<ga, 512, 0, stream>>>(Obuf, vt, out);
}

// Round 9
// 209.708 us; speedup vs baseline: 1.0271x; 1.0271x over previous
//
#include <hip/hip_runtime.h>
#include <hip/hip_bf16.h>

typedef unsigned short ushort_t;
typedef _Float16 half_t;
typedef __attribute__((ext_vector_type(8))) _Float16 h8;     // 8 fp16 (K=32 MFMA A/B frag)
typedef __attribute__((ext_vector_type(8))) short short8;
typedef __attribute__((ext_vector_type(4))) float f32x4;
typedef __attribute__((ext_vector_type(4))) float f4;

#define NB 4
#define SS 1024
#define HH 2048
#define NH 16
#define DD 128
#define MM (NB*SS)          // 4096 rows
#define NTOT 2304           // 2048 Q cols | 128 K | 128 V
#define COL_K 2048
#define COL_V 2176
#define KVB 64
#define L2E 1.44269504089f

__device__ __forceinline__ ushort_t f2h(float x) {
    half_t h = (half_t)x;
    return *(ushort_t*)&h;
}
__device__ __forceinline__ f32x4 mfma16h(h8 a, h8 b, f32x4 c) {
    return __builtin_amdgcn_mfma_f32_16x16x32_f16(a, b, c, 0, 0, 0);
}
__device__ __forceinline__ void load_lds16(const ushort_t* g, ushort_t* l) {
    __builtin_amdgcn_global_load_lds(
        (const __attribute__((address_space(1))) unsigned int*)g,
        (__attribute__((address_space(3))) unsigned int*)l,
        16, 0, 0);
}

// ---------------- f32 -> fp16 convert (hidden states) ----------------
__global__ void k_cvt(const float* __restrict__ src, ushort_t* __restrict__ dst, int n) {
    int i = (blockIdx.x * blockDim.x + threadIdx.x) * 8;
    if (i + 7 < n) {
        f4 a = *(const f4*)(src + i);
        f4 b = *(const f4*)(src + i + 4);
        short8 o;
        #pragma unroll
        for (int j = 0; j < 4; ++j) { o[j] = (short)f2h(a[j]); o[4 + j] = (short)f2h(b[j]); }
        *(short8*)(dst + i) = o;
    }
}

// ---------------- tiled weight transpose+convert: W[n][H][Dd] -> T[n*Dd+d][HH] ----------------
__global__ __launch_bounds__(256) void k_tw(const float* __restrict__ W,
                                            ushort_t* __restrict__ T, int Dd) {
    __shared__ ushort_t t[64][74];
    const int n = blockIdx.z;
    const int h0 = blockIdx.x * 64, d0 = blockIdx.y * 64;
    const int r = threadIdx.x >> 2, cg = (threadIdx.x & 3) * 16;
    const float* src = W + ((size_t)n * HH + h0 + r) * Dd + d0 + cg;
    #pragma unroll
    for (int v = 0; v < 4; ++v) {
        f4 a = *(const f4*)(src + v * 4);
        #pragma unroll
        for (int j = 0; j < 4; ++j) t[r][cg + v * 4 + j] = f2h(a[j]);
    }
    __syncthreads();
    short8 o0, o1;
    #pragma unroll
    for (int j = 0; j < 8; ++j) { o0[j] = (short)t[cg + j][r]; o1[j] = (short)t[cg + 8 + j][r]; }
    ushort_t* dst = T + ((size_t)(n * Dd + d0 + r)) * HH + h0 + cg;
    *(short8*)dst = o0;
    *(short8*)(dst + 8) = o1;
}

// ---------------- fp16 GEMM: O[M][NTOT] = A[M][HH] * B[NTOT][HH]^T + bias(fused) --------
__global__ __launch_bounds__(256) void k_gemm(
    const ushort_t* __restrict__ A, const ushort_t* __restrict__ B,
    const float* __restrict__ bq, const float* __restrict__ bk,
    const float* __restrict__ bvv, ushort_t* __restrict__ O) {

    constexpr int BK = 32;
    __shared__ ushort_t sA[128 * BK], sB[128 * BK];

    const int bid = blockIdx.x;
    const int swz = (bid & 7) * 72 + (bid >> 3);     // 576/8 = 72 per XCD, bijective
    const int m0 = (swz & 31) * 128;
    const int n0 = (swz >> 5) * 128;

    const int tid = threadIdx.x;
    const int w = tid >> 6, l = tid & 63;
    const int wr = w >> 1, wc = w & 1;
    f32x4 acc[4][4] = {};

    for (int kt = 0; kt < HH / BK; ++kt) {
        const int k0 = kt * BK;
        #pragma unroll
        for (int c = 0; c < 2; ++c) {
            int chunk = c * 4 + w;
            int idx = chunk * 512 + l * 8;
            int row = idx >> 5, kc = idx & 31;
            load_lds16(A + (size_t)(m0 + row) * HH + k0 + kc, &sA[chunk * 512]);
            load_lds16(B + (size_t)(n0 + row) * HH + k0 + kc, &sB[chunk * 512]);
        }
        __syncthreads();

        h8 a[4], b[4];
        #pragma unroll
        for (int i = 0; i < 4; ++i) {
            int ra = wr * 64 + i * 16 + (l & 15);
            int rb = wc * 64 + i * 16 + (l & 15);
            a[i] = *(const h8*)&sA[ra * 32 + (l >> 4) * 8];
            b[i] = *(const h8*)&sB[rb * 32 + (l >> 4) * 8];
        }
        #pragma unroll
        for (int i = 0; i < 4; ++i)
            #pragma unroll
            for (int j = 0; j < 4; ++j)
                acc[i][j] = mfma16h(a[i], b[j], acc[i][j]);
        __syncthreads();
    }

    #pragma unroll
    for (int i = 0; i < 4; ++i) {
        int row = m0 + wr * 64 + i * 16 + ((l >> 4) << 2);
        #pragma unroll
        for (int j = 0; j < 4; ++j) {
            int col = n0 + wc * 64 + j * 16 + (l & 15);
            float bv = (col < COL_K) ? bq[col]
                     : (col < COL_V) ? bk[col - COL_K]
                                     : bvv[col - COL_V];
            #pragma unroll
            for (int r = 0; r < 4; ++r) {
                float cv = acc[i][j][r] + bv;
                O[(size_t)(row + r) * NTOT + col] = f2h(cv);
            }
        }
    }
}

// ---------------- V transpose: O cols [COL_V..COL_V+128) -> Vt[128][MM] ----------------
__global__ __launch_bounds__(256) void k_transpose_v(const ushort_t* __restrict__ O,
                                                     ushort_t* __restrict__ Vt) {
    __shared__ ushort_t t[64][74];
    const int tid = threadIdx.x;
    const int bx = blockIdx.x;       // MM/64
    const int by = blockIdx.y;       // 128/64
    int r = tid >> 2, cg = (tid & 3) * 16;
    const ushort_t* src = &O[(size_t)(bx * 64 + r) * NTOT + COL_V + by * 64 + cg];
    short8 v0 = *(const short8*)src;
    short8 v1 = *(const short8*)(src + 8);
    #pragma unroll
    for (int j = 0; j < 8; ++j) { t[r][cg + j] = (ushort_t)v0[j]; t[r][cg + 8 + j] = (ushort_t)v1[j]; }
    __syncthreads();
    short8 o0, o1;
    #pragma unroll
    for (int j = 0; j < 8; ++j) { o0[j] = (short)t[cg + j][r]; o1[j] = (short)t[cg + 8 + j][r]; }
    ushort_t* dst = &Vt[(size_t)(by * 64 + r) * MM + bx * 64 + cg];
    *(short8*)dst = o0;
    *(short8*)(dst + 8) = o1;
}

// ---------------- flash attention: K via LDS, V prefetched to registers (T14) ----------
// grid (S/64, N, B), 256 thr = 4 waves x 16 q-rows. Permuted swapped QK^T (zero-shuffle
// K=32 PV frags). Per tile: issue 16 V h8-loads into vr[] right after the barrier,
// consume them in PV after QK^T+softmax (~600cy cover). LDS = K dbuf only (32 KB).
__global__ __launch_bounds__(256, 3) void k_attn(
    const ushort_t* __restrict__ O, const ushort_t* __restrict__ Vt,
    float* __restrict__ Out) {

    __shared__ ushort_t sK[2][KVB * 128];     // [t][128], mask (t&3)|((t>>3)&1)<<2, dbuf

    const int tid = threadIdx.x;
    const int w = tid >> 6, l = tid & 63;     // w in [0,4)
    const int lg = l >> 4, li = l & 15;
    const int q0 = blockIdx.x * 64;
    const int n = blockIdx.y, b = blockIdx.z;

    // Q fragments: rows q0 + w*16 + li
    h8 qv[4];
    {
        size_t base = ((size_t)(b * SS + q0 + w * 16 + li)) * NTOT + n * 128 + lg * 8;
        #pragma unroll
        for (int kk = 0; kk < 4; ++kk)
            qv[kk] = *(const h8*)&O[base + kk * 32];
    }

    f32x4 accO[8] = {};
    float m2 = -3.0e38f;
    float lsum = 0.f;

    auto stage = [&](int bi, int t0) {
        #pragma unroll
        for (int c = 0; c < 4; ++c) {
            int seg = c * 4 + w;                         // 16 segs over 4 waves
            int oe = seg * 512 + l * 8;
            int row = oe >> 7;
            int mk = (row & 3) | (((row >> 3) & 1) << 2);
            int ce = (oe & 127) ^ (mk << 3);
            size_t g = (size_t)(b * SS + t0 + row) * NTOT + COL_K + ce;
            load_lds16(O + g, &sK[bi][seg * 512]);
        }
    };

    stage(0, 0);
    constexpr int NT = SS / KVB;   // 16
    // V^T row base for this lane: Vt[d][MM], d = db*16 + li, col = b*SS + t
    const ushort_t* vtb = Vt + (size_t)b * SS + (size_t)li * MM + lg * 8;

    for (int it = 0; it < NT; ++it) {
        const int cur = it & 1;
        const int t0 = it * KVB;
        __syncthreads();                       // drains stage(cur)

        // ---- issue V-register prefetch FIRST (oldest vmcnt entries -> PV waits
        //      don't drain the K staging issued just after)
        h8 vr[16];
        #pragma unroll
        for (int db = 0; db < 8; ++db) {
            const ushort_t* vrow = vtb + (size_t)(db * 16) * MM + t0;
            vr[db * 2 + 0] = *(const h8*)&vrow[0];
            vr[db * 2 + 1] = *(const h8*)&vrow[32];
        }
        // ---- issue next K-tile staging
        if (it + 1 < NT) stage(cur ^ 1, t0 + KVB);
        const ushort_t* sKc = sK[cur];

        // ---- QK^T, permuted A-rows: reg r of s[ts] = S[t=(ts&1)*32+lg*8+(ts>>1)*4+r][q=li]
        f32x4 s[4] = {};
        __builtin_amdgcn_s_setprio(1);
        #pragma unroll
        for (int ts = 0; ts < 4; ++ts) {
            int trow = (ts & 1) * 32 + ((li >> 2) << 3) + ((ts >> 1) << 2) + (li & 3);
            int mk = (trow & 3) | (((trow >> 3) & 1) << 2);
            #pragma unroll
            for (int kk = 0; kk < 4; ++kk) {
                h8 kv = *(const h8*)&sKc[trow * 128 + ((kk * 32 + lg * 8) ^ (mk << 3))];
                s[ts] = mfma16h(kv, qv[kk], s[ts]);     // A=K, B=Q -> S^T
            }
        }
        __builtin_amdgcn_s_setprio(0);

        // ---- in-register online softmax (row q = li; 16 t-values per lane)
        float v = fmaxf(fmaxf(s[0][0], s[0][1]), fmaxf(s[0][2], s[0][3]));
        #pragma unroll
        for (int ts = 1; ts < 4; ++ts)
            v = fmaxf(v, fmaxf(fmaxf(s[ts][0], s[ts][1]), fmaxf(s[ts][2], s[ts][3])));
        v = fmaxf(v, __shfl_xor(v, 16));
        v = fmaxf(v, __shfl_xor(v, 32));
        float pm2 = v * L2E;

        if (!__all(pm2 <= m2 + 11.54f)) {   // defer-max, THR = 8 nats
            float mn = fmaxf(m2, pm2);
            float scl = exp2f(m2 - mn);
            lsum *= scl;
            #pragma unroll
            for (int db = 0; db < 8; ++db)
                #pragma unroll
                for (int r = 0; r < 4; ++r) accO[db][r] *= scl;
            m2 = mn;
        }

        h8 pb[2];
        #pragma unroll
        for (int ts = 0; ts < 4; ++ts)
            #pragma unroll
            for (int r = 0; r < 4; ++r) {
                float p = exp2f(fmaf(s[ts][r], L2E, -m2));
                lsum += p;
                pb[ts & 1][((ts >> 1) << 2) + r] = (half_t)p;
            }

        // ---- PV: K=32, V fragments already in registers
        __builtin_amdgcn_s_setprio(1);
        #pragma unroll
        for (int db = 0; db < 8; ++db) {
            accO[db] = mfma16h(vr[db * 2 + 0], pb[0], accO[db]);
            accO[db] = mfma16h(vr[db * 2 + 1], pb[1], accO[db]);
        }
        __builtin_amdgcn_s_setprio(0);
    }

    // ---- epilogue: finish denominator, normalize, write f32 [B][N][S][D]
    lsum += __shfl_xor(lsum, 16);
    lsum += __shfl_xor(lsum, 32);
    float inv = 1.0f / lsum;
    int q = q0 + w * 16 + li;
    size_t base = (((size_t)b * NH + n) * SS + q) * DD;
    #pragma unroll
    for (int db = 0; db < 8; ++db) {
        f4 o;
        #pragma unroll
        for (int r = 0; r < 4; ++r) o[r] = accO[db][r] * inv;
        *(f4*)&Out[base + db * 16 + lg * 4] = o;
    }
}

// ---------------- workspace layout (bytes) ----------------
#define OFF_HC    ((size_t)0)                          // hidden fp16 [MM][HH]
#define OFF_BC    (OFF_HC + (size_t)MM*HH*2)           // Bcat fp16 [NTOT][HH]
#define OFF_O     (OFF_BC + (size_t)NTOT*HH*2)         // O fp16 [MM][NTOT]
#define OFF_VT    (OFF_O + (size_t)MM*NTOT*2)          // Vt fp16 [128][MM]

extern "C" void kernel_launch(void* const* d_in, const int* in_sizes, int n_in,
                              void* d_out, int out_size, void* d_ws, size_t ws_size,
                              hipStream_t stream) {
    const float* hs = (const float*)d_in[0];
    const float* Wq = (const float*)d_in[1];
    const float* bq = (const float*)d_in[2];
    const float* Wk = (const float*)d_in[3];
    const float* bk = (const float*)d_in[4];
    const float* Wv = (const float*)d_in[5];
    const float* bv = (const float*)d_in[6];
    float* out = (float*)d_out;
    char* ws = (char*)d_ws;

    ushort_t* hc   = (ushort_t*)(ws + OFF_HC);
    ushort_t* bcat = (ushort_t*)(ws + OFF_BC);
    ushort_t* Obuf = (ushort_t*)(ws + OFF_O);
    ushort_t* vt   = (ushort_t*)(ws + OFF_VT);

    // prep
    k_cvt<<<(MM*HH)/(256*8), 256, 0, stream>>>(hs, hc, MM*HH);
    dim3 gwq(HH/64, DD/64, NH);
    k_tw<<<gwq, 256, 0, stream>>>(Wq, bcat, DD);
    dim3 gwk(HH/64, DD/64, 1);
    k_tw<<<gwk, 256, 0, stream>>>(Wk, bcat + (size_t)COL_K*HH, DD);
    k_tw<<<gwk, 256, 0, stream>>>(Wv, bcat + (size_t)COL_V*HH, DD);

    // merged projection GEMM: 4096 x 2304 x 2048, bias fused
    k_gemm<<<(MM/128)*(NTOT/128), 256, 0, stream>>>(hc, bcat, bq, bk, bv, Obuf);

    // V transpose
    dim3 gt(MM/64, DD/64);
    k_transpose_v<<<gt, 256, 0, stream>>>(Obuf, vt);

    // attention
    dim3 ga(SS/64, NH, NB);
    k_attn<<<ga, 256, 0, stream>>>(Obuf, vt, out);
}

// Round 10
// 208.696 us; speedup vs baseline: 1.0320x; 1.0048x over previous
//
#include <hip/hip_runtime.h>
#include <hip/hip_bf16.h>

typedef unsigned short ushort_t;
typedef _Float16 half_t;
typedef __attribute__((ext_vector_type(8))) _Float16 h8;     // 8 fp16 (K=32 MFMA A/B frag)
typedef __attribute__((ext_vector_type(8))) short short8;
typedef __attribute__((ext_vector_type(4))) float f32x4;
typedef __attribute__((ext_vector_type(4))) float f4;

#define NB 4
#define SS 1024
#define HH 2048
#define NH 16
#define DD 128
#define MM (NB*SS)          // 4096 rows
#define NTOT 2304           // 2048 Q cols | 128 K | 128 V
#define COL_K 2048
#define COL_V 2176
#define KVB 64
#define L2E 1.44269504089f

__device__ __forceinline__ ushort_t f2h(float x) {
    half_t h = (half_t)x;
    return *(ushort_t*)&h;
}
__device__ __forceinline__ f32x4 mfma16h(h8 a, h8 b, f32x4 c) {
    return __builtin_amdgcn_mfma_f32_16x16x32_f16(a, b, c, 0, 0, 0);
}
__device__ __forceinline__ void load_lds16(const ushort_t* g, ushort_t* l) {
    __builtin_amdgcn_global_load_lds(
        (const __attribute__((address_space(1))) unsigned int*)g,
        (__attribute__((address_space(3))) unsigned int*)l,
        16, 0, 0);
}

// ---------------- f32 -> fp16 convert (hidden states) ----------------
__global__ void k_cvt(const float* __restrict__ src, ushort_t* __restrict__ dst, int n) {
    int i = (blockIdx.x * blockDim.x + threadIdx.x) * 8;
    if (i + 7 < n) {
        f4 a = *(const f4*)(src + i);
        f4 b = *(const f4*)(src + i + 4);
        short8 o;
        #pragma unroll
        for (int j = 0; j < 4; ++j) { o[j] = (short)f2h(a[j]); o[4 + j] = (short)f2h(b[j]); }
        *(short8*)(dst + i) = o;
    }
}

// ---------------- tiled weight transpose+convert: W[n][H][Dd] -> T[n*Dd+d][HH] ----------------
__global__ __launch_bounds__(256) void k_tw(const float* __restrict__ W,
                                            ushort_t* __restrict__ T, int Dd) {
    __shared__ ushort_t t[64][74];
    const int n = blockIdx.z;
    const int h0 = blockIdx.x * 64, d0 = blockIdx.y * 64;
    const int r = threadIdx.x >> 2, cg = (threadIdx.x & 3) * 16;
    const float* src = W + ((size_t)n * HH + h0 + r) * Dd + d0 + cg;
    #pragma unroll
    for (int v = 0; v < 4; ++v) {
        f4 a = *(const f4*)(src + v * 4);
        #pragma unroll
        for (int j = 0; j < 4; ++j) t[r][cg + v * 4 + j] = f2h(a[j]);
    }
    __syncthreads();
    short8 o0, o1;
    #pragma unroll
    for (int j = 0; j < 8; ++j) { o0[j] = (short)t[cg + j][r]; o1[j] = (short)t[cg + 8 + j][r]; }
    ushort_t* dst = T + ((size_t)(n * Dd + d0 + r)) * HH + h0 + cg;
    *(short8*)dst = o0;
    *(short8*)(dst + 8) = o1;
}

// ---------------- fp16 GEMM: O[M][NTOT] = A[M][HH] * B[NTOT][HH]^T + bias(fused) --------
__global__ __launch_bounds__(256) void k_gemm(
    const ushort_t* __restrict__ A, const ushort_t* __restrict__ B,
    const float* __restrict__ bq, const float* __restrict__ bk,
    const float* __restrict__ bvv, ushort_t* __restrict__ O) {

    constexpr int BK = 32;
    __shared__ ushort_t sA[128 * BK], sB[128 * BK];

    const int bid = blockIdx.x;
    const int swz = (bid & 7) * 72 + (bid >> 3);     // 576/8 = 72 per XCD, bijective
    const int m0 = (swz & 31) * 128;
    const int n0 = (swz >> 5) * 128;

    const int tid = threadIdx.x;
    const int w = tid >> 6, l = tid & 63;
    const int wr = w >> 1, wc = w & 1;
    f32x4 acc[4][4] = {};

    for (int kt = 0; kt < HH / BK; ++kt) {
        const int k0 = kt * BK;
        #pragma unroll
        for (int c = 0; c < 2; ++c) {
            int chunk = c * 4 + w;
            int idx = chunk * 512 + l * 8;
            int row = idx >> 5, kc = idx & 31;
            load_lds16(A + (size_t)(m0 + row) * HH + k0 + kc, &sA[chunk * 512]);
            load_lds16(B + (size_t)(n0 + row) * HH + k0 + kc, &sB[chunk * 512]);
        }
        __syncthreads();

        h8 a[4], b[4];
        #pragma unroll
        for (int i = 0; i < 4; ++i) {
            int ra = wr * 64 + i * 16 + (l & 15);
            int rb = wc * 64 + i * 16 + (l & 15);
            a[i] = *(const h8*)&sA[ra * 32 + (l >> 4) * 8];
            b[i] = *(const h8*)&sB[rb * 32 + (l >> 4) * 8];
        }
        #pragma unroll
        for (int i = 0; i < 4; ++i)
            #pragma unroll
            for (int j = 0; j < 4; ++j)
                acc[i][j] = mfma16h(a[i], b[j], acc[i][j]);
        __syncthreads();
    }

    #pragma unroll
    for (int i = 0; i < 4; ++i) {
        int row = m0 + wr * 64 + i * 16 + ((l >> 4) << 2);
        #pragma unroll
        for (int j = 0; j < 4; ++j) {
            int col = n0 + wc * 64 + j * 16 + (l & 15);
            float bv = (col < COL_K) ? bq[col]
                     : (col < COL_V) ? bk[col - COL_K]
                                     : bvv[col - COL_V];
            #pragma unroll
            for (int r = 0; r < 4; ++r) {
                float cv = acc[i][j][r] + bv;
                O[(size_t)(row + r) * NTOT + col] = f2h(cv);
            }
        }
    }
}

// ---------------- V transpose: O cols [COL_V..COL_V+128) -> Vt[128][MM] ----------------
__global__ __launch_bounds__(256) void k_transpose_v(const ushort_t* __restrict__ O,
                                                     ushort_t* __restrict__ Vt) {
    __shared__ ushort_t t[64][74];
    const int tid = threadIdx.x;
    const int bx = blockIdx.x;       // MM/64
    const int by = blockIdx.y;       // 128/64
    int r = tid >> 2, cg = (tid & 3) * 16;
    const ushort_t* src = &O[(size_t)(bx * 64 + r) * NTOT + COL_V + by * 64 + cg];
    short8 v0 = *(const short8*)src;
    short8 v1 = *(const short8*)(src + 8);
    #pragma unroll
    for (int j = 0; j < 8; ++j) { t[r][cg + j] = (ushort_t)v0[j]; t[r][cg + 8 + j] = (ushort_t)v1[j]; }
    __syncthreads();
    short8 o0, o1;
    #pragma unroll
    for (int j = 0; j < 8; ++j) { o0[j] = (short)t[cg + j][r]; o1[j] = (short)t[cg + 8 + j][r]; }
    ushort_t* dst = &Vt[(size_t)(by * 64 + r) * MM + bx * 64 + cg];
    *(short8*)dst = o0;
    *(short8*)(dst + 8) = o1;
}

// ---------------- flash attention: K via LDS, V via asm-forced register prefetch --------
// grid (S/64, N, B), 256 thr = 4 waves x 16 q-rows. Permuted swapped QK^T (zero-shuffle
// K=32 PV frags). Per tile: 16 V h8-loads issued via asm volatile (un-sinkable) right
// after the barrier, BEFORE K staging; counted s_waitcnt vmcnt(4) + sched_barrier before
// PV consumes them. LDS = K dbuf only (32 KB).
__global__ __launch_bounds__(256, 2) void k_attn(
    const ushort_t* __restrict__ O, const ushort_t* __restrict__ Vt,
    float* __restrict__ Out) {

    __shared__ ushort_t sK[2][KVB * 128];     // [t][128], mask (t&3)|((t>>3)&1)<<2, dbuf

    const int tid = threadIdx.x;
    const int w = tid >> 6, l = tid & 63;     // w in [0,4)
    const int lg = l >> 4, li = l & 15;
    const int q0 = blockIdx.x * 64;
    const int n = blockIdx.y, b = blockIdx.z;

    // Q fragments: rows q0 + w*16 + li
    h8 qv[4];
    {
        size_t base = ((size_t)(b * SS + q0 + w * 16 + li)) * NTOT + n * 128 + lg * 8;
        #pragma unroll
        for (int kk = 0; kk < 4; ++kk)
            qv[kk] = *(const h8*)&O[base + kk * 32];
    }

    f32x4 accO[8] = {};
    float m2 = -3.0e38f;
    float lsum = 0.f;

    auto stage = [&](int bi, int t0) {
        #pragma unroll
        for (int c = 0; c < 4; ++c) {
            int seg = c * 4 + w;                         // 16 segs over 4 waves
            int oe = seg * 512 + l * 8;
            int row = oe >> 7;
            int mk = (row & 3) | (((row >> 3) & 1) << 2);
            int ce = (oe & 127) ^ (mk << 3);
            size_t g = (size_t)(b * SS + t0 + row) * NTOT + COL_K + ce;
            load_lds16(O + g, &sK[bi][seg * 512]);
        }
    };

    stage(0, 0);
    constexpr int NT = SS / KVB;   // 16
    // V^T base for this lane: Vt[d][MM], d = db*16 + li, col = b*SS + t0 + lg*8
    const ushort_t* vtb = Vt + (size_t)b * SS + (size_t)li * MM + lg * 8;

    for (int it = 0; it < NT; ++it) {
        const int cur = it & 1;
        const int t0 = it * KVB;
        __syncthreads();                       // drains stage(cur) (+ all vmcnt)

        // ---- V prefetch: 16 h8 via asm volatile (producer = asm -> cannot be sunk).
        //      Issued BEFORE K staging so vmcnt counting is {V x16 oldest, K x4 newest}.
        h8 vr[16];
        #pragma unroll
        for (int db = 0; db < 8; ++db) {
            const ushort_t* p = vtb + (size_t)(db * 16) * MM + t0;
            asm volatile("global_load_dwordx4 %0, %2, off\n\t"
                         "global_load_dwordx4 %1, %2, off offset:64"
                         : "=v"(vr[2 * db]), "=v"(vr[2 * db + 1])
                         : "v"(p));
        }
        // ---- issue next K-tile staging (4 loads, newest in vmcnt queue)
        if (it + 1 < NT) stage(cur ^ 1, t0 + KVB);
        const ushort_t* sKc = sK[cur];

        // ---- QK^T, permuted A-rows: reg r of s[ts] = S[t=(ts&1)*32+lg*8+(ts>>1)*4+r][q=li]
        f32x4 s[4] = {};
        __builtin_amdgcn_s_setprio(1);
        #pragma unroll
        for (int ts = 0; ts < 4; ++ts) {
            int trow = (ts & 1) * 32 + ((li >> 2) << 3) + ((ts >> 1) << 2) + (li & 3);
            int mk = (trow & 3) | (((trow >> 3) & 1) << 2);
            #pragma unroll
            for (int kk = 0; kk < 4; ++kk) {
                h8 kv = *(const h8*)&sKc[trow * 128 + ((kk * 32 + lg * 8) ^ (mk << 3))];
                s[ts] = mfma16h(kv, qv[kk], s[ts]);     // A=K, B=Q -> S^T
            }
        }
        __builtin_amdgcn_s_setprio(0);

        // ---- in-register online softmax (row q = li; 16 t-values per lane)
        float v = fmaxf(fmaxf(s[0][0], s[0][1]), fmaxf(s[0][2], s[0][3]));
        #pragma unroll
        for (int ts = 1; ts < 4; ++ts)
            v = fmaxf(v, fmaxf(fmaxf(s[ts][0], s[ts][1]), fmaxf(s[ts][2], s[ts][3])));
        v = fmaxf(v, __shfl_xor(v, 16));
        v = fmaxf(v, __shfl_xor(v, 32));
        float pm2 = v * L2E;

        if (!__all(pm2 <= m2 + 11.54f)) {   // defer-max, THR = 8 nats
            float mn = fmaxf(m2, pm2);
            float scl = exp2f(m2 - mn);
            lsum *= scl;
            #pragma unroll
            for (int db = 0; db < 8; ++db)
                #pragma unroll
                for (int r = 0; r < 4; ++r) accO[db][r] *= scl;
            m2 = mn;
        }

        h8 pb[2];
        #pragma unroll
        for (int ts = 0; ts < 4; ++ts)
            #pragma unroll
            for (int r = 0; r < 4; ++r) {
                float p = exp2f(fmaf(s[ts][r], L2E, -m2));
                lsum += p;
                pb[ts & 1][((ts >> 1) << 2) + r] = (half_t)p;
            }

        // ---- counted drain: V loads (oldest 16) done; K staging (newest 4) stays in flight
        if (it + 1 < NT) asm volatile("s_waitcnt vmcnt(4)" ::: "memory");
        else             asm volatile("s_waitcnt vmcnt(0)" ::: "memory");
        __builtin_amdgcn_sched_barrier(0);     // rule #18: pin MFMAs below the wait

        // ---- PV: K=32, V fragments in registers
        __builtin_amdgcn_s_setprio(1);
        #pragma unroll
        for (int db = 0; db < 8; ++db) {
            accO[db] = mfma16h(vr[2 * db + 0], pb[0], accO[db]);
            accO[db] = mfma16h(vr[2 * db + 1], pb[1], accO[db]);
        }
        __builtin_amdgcn_s_setprio(0);
    }

    // ---- epilogue: finish denominator, normalize, write f32 [B][N][S][D]
    lsum += __shfl_xor(lsum, 16);
    lsum += __shfl_xor(lsum, 32);
    float inv = 1.0f / lsum;
    int q = q0 + w * 16 + li;
    size_t base = (((size_t)b * NH + n) * SS + q) * DD;
    #pragma unroll
    for (int db = 0; db < 8; ++db) {
        f4 o;
        #pragma unroll
        for (int r = 0; r < 4; ++r) o[r] = accO[db][r] * inv;
        *(f4*)&Out[base + db * 16 + lg * 4] = o;
    }
}

// ---------------- workspace layout (bytes) ----------------
#define OFF_HC    ((size_t)0)                          // hidden fp16 [MM][HH]
#define OFF_BC    (OFF_HC + (size_t)MM*HH*2)           // Bcat fp16 [NTOT][HH]
#define OFF_O     (OFF_BC + (size_t)NTOT*HH*2)         // O fp16 [MM][NTOT]
#define OFF_VT    (OFF_O + (size_t)MM*NTOT*2)          // Vt fp16 [128][MM]

extern "C" void kernel_launch(void* const* d_in, const int* in_sizes, int n_in,
                              void* d_out, int out_size, void* d_ws, size_t ws_size,
                              hipStream_t stream) {
    const float* hs = (const float*)d_in[0];
    const float* Wq = (const float*)d_in[1];
    const float* bq = (const float*)d_in[2];
    const float* Wk = (const float*)d_in[3];
    const float* bk = (const float*)d_in[4];
    const float* Wv = (const float*)d_in[5];
    const float* bv = (const float*)d_in[6];
    float* out = (float*)d_out;
    char* ws = (char*)d_ws;

    ushort_t* hc   = (ushort_t*)(ws + OFF_HC);
    ushort_t* bcat = (ushort_t*)(ws + OFF_BC);
    ushort_t* Obuf = (ushort_t*)(ws + OFF_O);
    ushort_t* vt   = (ushort_t*)(ws + OFF_VT);

    // prep
    k_cvt<<<(MM*HH)/(256*8), 256, 0, stream>>>(hs, hc, MM*HH);
    dim3 gwq(HH/64, DD/64, NH);
    k_tw<<<gwq, 256, 0, stream>>>(Wq, bcat, DD);
    dim3 gwk(HH/64, DD/64, 1);
    k_tw<<<gwk, 256, 0, stream>>>(Wk, bcat + (size_t)COL_K*HH, DD);
    k_tw<<<gwk, 256, 0, stream>>>(Wv, bcat + (size_t)COL_V*HH, DD);

    // merged projection GEMM: 4096 x 2304 x 2048, bias fused
    k_gemm<<<(MM/128)*(NTOT/128), 256, 0, stream>>>(hc, bcat, bq, bk, bv, Obuf);

    // V transpose
    dim3 gt(MM/64, DD/64);
    k_transpose_v<<<gt, 256, 0, stream>>>(Obuf, vt);

    // attention
    dim3 ga(SS/64, NH, NB);
    k_attn<<<ga, 256, 0, stream>>>(Obuf, vt, out);
}

// Round 11
// 128.799 us; speedup vs baseline: 1.6723x; 1.6203x over previous
//
#include <hip/hip_runtime.h>
#include <hip/hip_bf16.h>

typedef unsigned short ushort_t;
typedef _Float16 half_t;
typedef __attribute__((ext_vector_type(8))) _Float16 h8;     // 8 fp16 (K=32 MFMA A/B frag)
typedef __attribute__((ext_vector_type(8))) short short8;
typedef __attribute__((ext_vector_type(4))) short short4_t;  // 8B store
typedef __attribute__((ext_vector_type(4))) float f32x4;
typedef __attribute__((ext_vector_type(4))) float f4;

#define NB 4
#define SS 1024
#define HH 2048
#define NH 16
#define DD 128
#define MM (NB*SS)          // 4096 rows
#define NTOT 2304           // 2048 Q cols | 128 K | 128 V
#define COL_K 2048
#define COL_V 2176
#define KVB 64
#define L2E 1.44269504089f

__device__ __forceinline__ ushort_t f2h(float x) {
    half_t h = (half_t)x;
    return *(ushort_t*)&h;
}
__device__ __forceinline__ f32x4 mfma16h(h8 a, h8 b, f32x4 c) {
    return __builtin_amdgcn_mfma_f32_16x16x32_f16(a, b, c, 0, 0, 0);
}
__device__ __forceinline__ void load_lds16(const ushort_t* g, ushort_t* l) {
    __builtin_amdgcn_global_load_lds(
        (const __attribute__((address_space(1))) unsigned int*)g,
        (__attribute__((address_space(3))) unsigned int*)l,
        16, 0, 0);
}

// ---------------- f32 -> fp16 convert (hidden states) ----------------
__global__ void k_cvt(const float* __restrict__ src, ushort_t* __restrict__ dst, int n) {
    int i = (blockIdx.x * blockDim.x + threadIdx.x) * 8;
    if (i + 7 < n) {
        f4 a = *(const f4*)(src + i);
        f4 b = *(const f4*)(src + i + 4);
        short8 o;
        #pragma unroll
        for (int j = 0; j < 4; ++j) { o[j] = (short)f2h(a[j]); o[4 + j] = (short)f2h(b[j]); }
        *(short8*)(dst + i) = o;
    }
}

// ---------------- tiled weight transpose+convert: W[n][H][Dd] -> T[n*Dd+d][HH] ----------------
__global__ __launch_bounds__(256) void k_tw(const float* __restrict__ W,
                                            ushort_t* __restrict__ T, int Dd) {
    __shared__ ushort_t t[64][74];
    const int n = blockIdx.z;
    const int h0 = blockIdx.x * 64, d0 = blockIdx.y * 64;
    const int r = threadIdx.x >> 2, cg = (threadIdx.x & 3) * 16;
    const float* src = W + ((size_t)n * HH + h0 + r) * Dd + d0 + cg;
    #pragma unroll
    for (int v = 0; v < 4; ++v) {
        f4 a = *(const f4*)(src + v * 4);
        #pragma unroll
        for (int j = 0; j < 4; ++j) t[r][cg + v * 4 + j] = f2h(a[j]);
    }
    __syncthreads();
    short8 o0, o1;
    #pragma unroll
    for (int j = 0; j < 8; ++j) { o0[j] = (short)t[cg + j][r]; o1[j] = (short)t[cg + 8 + j][r]; }
    ushort_t* dst = T + ((size_t)(n * Dd + d0 + r)) * HH + h0 + cg;
    *(short8*)dst = o0;
    *(short8*)(dst + 8) = o1;
}

// ---------------- fp16 GEMM: O[M][NTOT] = A[M][HH] * B[NTOT][HH]^T + bias(fused) --------
// V n-tile (cols >= COL_V) is written TRANSPOSED to Vt[col'][row] (8B short4 stores),
// O-write skipped for those cols -> k_transpose_v kernel deleted.
__global__ __launch_bounds__(256) void k_gemm(
    const ushort_t* __restrict__ A, const ushort_t* __restrict__ B,
    const float* __restrict__ bq, const float* __restrict__ bk,
    const float* __restrict__ bvv, ushort_t* __restrict__ O,
    ushort_t* __restrict__ Vt) {

    constexpr int BK = 32;
    __shared__ ushort_t sA[128 * BK], sB[128 * BK];

    const int bid = blockIdx.x;
    const int swz = (bid & 7) * 72 + (bid >> 3);     // 576/8 = 72 per XCD, bijective
    const int m0 = (swz & 31) * 128;
    const int n0 = (swz >> 5) * 128;

    const int tid = threadIdx.x;
    const int w = tid >> 6, l = tid & 63;
    const int wr = w >> 1, wc = w & 1;
    f32x4 acc[4][4] = {};

    for (int kt = 0; kt < HH / BK; ++kt) {
        const int k0 = kt * BK;
        #pragma unroll
        for (int c = 0; c < 2; ++c) {
            int chunk = c * 4 + w;
            int idx = chunk * 512 + l * 8;
            int row = idx >> 5, kc = idx & 31;
            load_lds16(A + (size_t)(m0 + row) * HH + k0 + kc, &sA[chunk * 512]);
            load_lds16(B + (size_t)(n0 + row) * HH + k0 + kc, &sB[chunk * 512]);
        }
        __syncthreads();

        h8 a[4], b[4];
        #pragma unroll
        for (int i = 0; i < 4; ++i) {
            int ra = wr * 64 + i * 16 + (l & 15);
            int rb = wc * 64 + i * 16 + (l & 15);
            a[i] = *(const h8*)&sA[ra * 32 + (l >> 4) * 8];
            b[i] = *(const h8*)&sB[rb * 32 + (l >> 4) * 8];
        }
        #pragma unroll
        for (int i = 0; i < 4; ++i)
            #pragma unroll
            for (int j = 0; j < 4; ++j)
                acc[i][j] = mfma16h(a[i], b[j], acc[i][j]);
        __syncthreads();
    }

    #pragma unroll
    for (int i = 0; i < 4; ++i) {
        int row = m0 + wr * 64 + i * 16 + ((l >> 4) << 2);
        #pragma unroll
        for (int j = 0; j < 4; ++j) {
            int col = n0 + wc * 64 + j * 16 + (l & 15);
            float bv = (col < COL_K) ? bq[col]
                     : (col < COL_V) ? bk[col - COL_K]
                                     : bvv[col - COL_V];
            if (col < COL_V) {
                #pragma unroll
                for (int r = 0; r < 4; ++r)
                    O[(size_t)(row + r) * NTOT + col] = f2h(acc[i][j][r] + bv);
            } else {
                short4_t o;
                #pragma unroll
                for (int r = 0; r < 4; ++r) o[r] = (short)f2h(acc[i][j][r] + bv);
                *(short4_t*)&Vt[(size_t)(col - COL_V) * MM + row] = o;
            }
        }
    }
}

// ---------------- flash attention: 8 waves x 16 q-rows, permuted QK^T, K=32 PV ----------
// grid (S/128, N, B), 512 thr. K and V^T tiles via LDS (shared across 8 waves — the
// r8/r9/r10 lesson: per-wave register V is 8x-redundant fetch). K swizzle is 4-BIT
// (row&3)|(((row>>3)&3)<<2 -> 16 distinct slots per read instruction (conflict-free;
// the old 3-bit mask aliased lg groups -> 4-way). T5 setprio around MFMA clusters.
__global__ __launch_bounds__(512, 4) void k_attn(
    const ushort_t* __restrict__ O, const ushort_t* __restrict__ Vt,
    float* __restrict__ Out) {

    __shared__ ushort_t sK[2][KVB * 128];     // [t][128], 4-bit mask swizzle, dbuf
    __shared__ ushort_t sVt[2][128 * KVB];    // [d][KVB], mask d&7, dbuf

    const int tid = threadIdx.x;
    const int w = tid >> 6, l = tid & 63;     // w in [0,8)
    const int lg = l >> 4, li = l & 15;
    const int q0 = blockIdx.x * 128;
    const int n = blockIdx.y, b = blockIdx.z;

    // Q fragments: rows q0 + w*16 + li
    h8 qv[4];
    {
        size_t base = ((size_t)(b * SS + q0 + w * 16 + li)) * NTOT + n * 128 + lg * 8;
        #pragma unroll
        for (int kk = 0; kk < 4; ++kk)
            qv[kk] = *(const h8*)&O[base + kk * 32];
    }

    f32x4 accO[8] = {};
    float m2 = -3.0e38f;
    float lsum = 0.f;

    auto stage = [&](int bi, int t0) {
        #pragma unroll
        for (int c = 0; c < 2; ++c) {
            int seg = c * 8 + w;                         // 16 segs over 8 waves
            int oe = seg * 512 + l * 8;
            int row = oe >> 7;
            int mk = (row & 3) | (((row >> 3) & 3) << 2);   // 4-bit: 16 distinct slots
            int ce = (oe & 127) ^ (mk << 3);
            size_t g = (size_t)(b * SS + t0 + row) * NTOT + COL_K + ce;
            load_lds16(O + g, &sK[bi][seg * 512]);
        }
        #pragma unroll
        for (int c = 0; c < 2; ++c) {
            int seg = c * 8 + w;
            int oe = seg * 512 + l * 8;
            int row = oe >> 6;
            int ce = (oe & 63) ^ ((row & 7) << 3);
            size_t g = (size_t)row * MM + b * SS + t0 + ce;
            load_lds16(Vt + g, &sVt[bi][seg * 512]);
        }
    };

    stage(0, 0);
    constexpr int NT = SS / KVB;   // 16

    for (int it = 0; it < NT; ++it) {
        const int cur = it & 1;
        const int t0 = it * KVB;
        __syncthreads();                       // drains stage(cur)
        if (it + 1 < NT) stage(cur ^ 1, t0 + KVB);
        const ushort_t* sKc = sK[cur];
        const ushort_t* sVc = sVt[cur];

        // ---- QK^T, permuted A-rows: reg r of s[ts] = S[t=(ts&1)*32+lg*8+(ts>>1)*4+r][q=li]
        f32x4 s[4] = {};
        __builtin_amdgcn_s_setprio(1);
        #pragma unroll
        for (int ts = 0; ts < 4; ++ts) {
            int trow = (ts & 1) * 32 + ((li >> 2) << 3) + ((ts >> 1) << 2) + (li & 3);
            int mk = (trow & 3) | (((trow >> 3) & 3) << 2);
            #pragma unroll
            for (int kk = 0; kk < 4; ++kk) {
                h8 kv = *(const h8*)&sKc[trow * 128 + ((kk * 32 + lg * 8) ^ (mk << 3))];
                s[ts] = mfma16h(kv, qv[kk], s[ts]);     // A=K, B=Q -> S^T
            }
        }
        __builtin_amdgcn_s_setprio(0);

        // ---- in-register online softmax (row q = li; 16 t-values per lane)
        float v = fmaxf(fmaxf(s[0][0], s[0][1]), fmaxf(s[0][2], s[0][3]));
        #pragma unroll
        for (int ts = 1; ts < 4; ++ts)
            v = fmaxf(v, fmaxf(fmaxf(s[ts][0], s[ts][1]), fmaxf(s[ts][2], s[ts][3])));
        v = fmaxf(v, __shfl_xor(v, 16));
        v = fmaxf(v, __shfl_xor(v, 32));
        float pm2 = v * L2E;

        if (!__all(pm2 <= m2 + 11.54f)) {   // defer-max, THR = 8 nats
            float mn = fmaxf(m2, pm2);
            float scl = exp2f(m2 - mn);
            lsum *= scl;
            #pragma unroll
            for (int db = 0; db < 8; ++db)
                #pragma unroll
                for (int r = 0; r < 4; ++r) accO[db][r] *= scl;
            m2 = mn;
        }

        h8 pb[2];
        #pragma unroll
        for (int ts = 0; ts < 4; ++ts)
            #pragma unroll
            for (int r = 0; r < 4; ++r) {
                float p = exp2f(fmaf(s[ts][r], L2E, -m2));
                lsum += p;
                pb[ts & 1][((ts >> 1) << 2) + r] = (half_t)p;
            }

        // ---- PV: K=32, b128 V^T reads from LDS (conflict-free 8-slot pattern)
        __builtin_amdgcn_s_setprio(1);
        #pragma unroll
        for (int db = 0; db < 8; ++db) {
            int d = db * 16 + li;
            const ushort_t* vbase = &sVc[d * KVB];
            int sw = (d & 7) << 3;
            #pragma unroll
            for (int ks = 0; ks < 2; ++ks) {
                h8 va = *(const h8*)&vbase[(ks * 32 + lg * 8) ^ sw];
                accO[db] = mfma16h(va, pb[ks], accO[db]);
            }
        }
        __builtin_amdgcn_s_setprio(0);
    }

    // ---- epilogue: finish denominator, normalize, write f32 [B][N][S][D]
    lsum += __shfl_xor(lsum, 16);
    lsum += __shfl_xor(lsum, 32);
    float inv = 1.0f / lsum;
    int q = q0 + w * 16 + li;
    size_t base = (((size_t)b * NH + n) * SS + q) * DD;
    #pragma unroll
    for (int db = 0; db < 8; ++db) {
        f4 o;
        #pragma unroll
        for (int r = 0; r < 4; ++r) o[r] = accO[db][r] * inv;
        *(f4*)&Out[base + db * 16 + lg * 4] = o;
    }
}

// ---------------- workspace layout (bytes) ----------------
#define OFF_HC    ((size_t)0)                          // hidden fp16 [MM][HH]
#define OFF_BC    (OFF_HC + (size_t)MM*HH*2)           // Bcat fp16 [NTOT][HH]
#define OFF_O     (OFF_BC + (size_t)NTOT*HH*2)         // O fp16 [MM][NTOT]
#define OFF_VT    (OFF_O + (size_t)MM*NTOT*2)          // Vt fp16 [128][MM]

extern "C" void kernel_launch(void* const* d_in, const int* in_sizes, int n_in,
                              void* d_out, int out_size, void* d_ws, size_t ws_size,
                              hipStream_t stream) {
    const float* hs = (const float*)d_in[0];
    const float* Wq = (const float*)d_in[1];
    const float* bq = (const float*)d_in[2];
    const float* Wk = (const float*)d_in[3];
    const float* bk = (const float*)d_in[4];
    const float* Wv = (const float*)d_in[5];
    const float* bv = (const float*)d_in[6];
    float* out = (float*)d_out;
    char* ws = (char*)d_ws;

    ushort_t* hc   = (ushort_t*)(ws + OFF_HC);
    ushort_t* bcat = (ushort_t*)(ws + OFF_BC);
    ushort_t* Obuf = (ushort_t*)(ws + OFF_O);
    ushort_t* vt   = (ushort_t*)(ws + OFF_VT);

    // prep
    k_cvt<<<(MM*HH)/(256*8), 256, 0, stream>>>(hs, hc, MM*HH);
    dim3 gwq(HH/64, DD/64, NH);
    k_tw<<<gwq, 256, 0, stream>>>(Wq, bcat, DD);
    dim3 gwk(HH/64, DD/64, 1);
    k_tw<<<gwk, 256, 0, stream>>>(Wk, bcat + (size_t)COL_K*HH, DD);
    k_tw<<<gwk, 256, 0, stream>>>(Wv, bcat + (size_t)COL_V*HH, DD);

    // merged projection GEMM: 4096 x 2304 x 2048, bias fused, V^T written directly
    k_gemm<<<(MM/128)*(NTOT/128), 256, 0, stream>>>(hc, bcat, bq, bk, bv, Obuf, vt);

    // attention
    dim3 ga(SS/128, NH, NB);
    k_attn<<<ga, 512, 0, stream>>>(Obuf, vt, out);
}